// Round 12
// baseline (370.976 us; speedup 1.0000x reference)
//
#include <hip/hip_runtime.h>
#include <hip/hip_bf16.h>
#include <hip/hip_fp16.h>

// ---------------------------------------------------------------------------
// 3-layer GAT encoder. N=50000, E=1600000 (+N self loops), H=2 (layers 1-2),
// F=64 per head, F_IN=128.
// R1: scatter+atomics -> CSR-by-dst + register gather.
// R2: CSR build via LDS-aggregated counting sort.
// R3: gather software pipeline; al fused into GEMM epilogue.
// R4: h fp16.  R5/R6: fast scan; bucket histogram.
// R7: MFMA GEMM.  R8 FAILED (cooperative CSR). R9: revert to split CSR.
// R10: GEMM2/GEMM3 fused into gather epilogues; pipeline gemm1 ->
//      [gather+gemm2] -> [gather+gemm3] -> gather3.
// R11: fused kernel reads W from global/L2 (35KB LDS freed -> occupancy
//      4->8 blocks/CU); edge_partition chunk 8192->2048 (4x blocks).
// ---------------------------------------------------------------------------

#define ELU(x) ((x) > 0.f ? (x) : (__expf(x) - 1.f))
#define BSH 8                       // 256 nodes per bucket

typedef _Float16 f16x8 __attribute__((ext_vector_type(8)));
typedef float    f32x4 __attribute__((ext_vector_type(4)));

// ---------------- phase0: Wt builds + per-block dst histogram --------------
__global__ __launch_bounds__(256) void phase0(
    const float* __restrict__ W1, __half* __restrict__ Wt1,
    const float* __restrict__ W2, __half* __restrict__ Wt2,
    const float* __restrict__ W3, __half* __restrict__ Wt3,
    const int* __restrict__ ei, int* __restrict__ bhist_rows, int E_, int HB)
{
    const int t = threadIdx.x;
    const int b = blockIdx.x;
    if (b < 160) {                                   // Wt[n][k] = (h) W[k][n]
        const float* W; __half* Wt; int N, base;
        if (b < 64)       { W = W1; Wt = Wt1; N = 128; base = b; }
        else if (b < 128) { W = W2; Wt = Wt2; N = 128; base = b - 64; }
        else              { W = W3; Wt = Wt3; N = 64;  base = b - 128; }
        int idx = base * 256 + t;
        if (idx < N * 128) {
            int nn = idx >> 7, k = idx & 127;
            Wt[idx] = __float2half(W[k * N + nn]);
        }
    } else {                                         // dst histogram row
        __shared__ int cnt[256];
        int hb = b - 160;
        cnt[t] = 0;
        __syncthreads();
        const long long e0 = (long long)hb * 8192;
        for (int i = t; i < 8192; i += 256) {
            long long e = e0 + i;
            if (e >= E_) break;
            atomicAdd(&cnt[ei[E_ + e] >> BSH], 1);
        }
        __syncthreads();
        bhist_rows[hb * 256 + t] = cnt[t];
    }
}

// one block: column-sum hist rows + self loops, scan -> boff/bcur
__global__ __launch_bounds__(256) void bucket_scan(
    const int* __restrict__ bhist_rows, int HB, int* __restrict__ boff,
    int* __restrict__ bcur, int n, int NB)
{
    __shared__ int sm[256];
    const int t = threadIdx.x;
    int v = 0;
    for (int r = 0; r < HB; r++) v += bhist_rows[r * 256 + t];
    int nodes = n - (t << BSH);
    nodes = nodes < 0 ? 0 : (nodes > 256 ? 256 : nodes);
    v = (t < NB) ? (v + nodes) : 0;              // + self loops
    sm[t] = v;
    __syncthreads();
    for (int d = 1; d < 256; d <<= 1) {
        int x = (t >= d) ? sm[t - d] : 0;
        __syncthreads();
        sm[t] += x;
        __syncthreads();
    }
    if (t < NB) {
        boff[t + 1] = sm[t];
        bcur[t] = sm[t] - v;
    }
    if (t == 0) boff[0] = 0;
}

// partition edges into dst-buckets, LDS-aggregated; 2048 edges/block.
// packed entry: src (bits 0..15) | dst_local (bits 16..23)
__global__ __launch_bounds__(256) void edge_partition(
    const int* __restrict__ ei, int* __restrict__ bcur,
    int* __restrict__ part, int E_, int Etot)
{
    __shared__ int cnt[256];
    __shared__ int base[256];
    const int t = threadIdx.x;
    const long long e0 = (long long)blockIdx.x * 2048;
    cnt[t] = 0;
    __syncthreads();
    for (int i = t; i < 2048; i += 256) {
        long long e = e0 + i;
        if (e >= Etot) break;
        int dst = (e < E_) ? ei[E_ + e] : (int)(e - E_);
        atomicAdd(&cnt[dst >> BSH], 1);
    }
    __syncthreads();
    if (cnt[t] > 0) base[t] = atomicAdd(&bcur[t], cnt[t]);
    __syncthreads();
    cnt[t] = 0;
    __syncthreads();
    for (int i = t; i < 2048; i += 256) {
        long long e = e0 + i;
        if (e >= Etot) break;
        int src, dst;
        if (e < E_) { src = ei[e]; dst = ei[E_ + e]; }
        else        { src = dst = (int)(e - E_); }
        int b = dst >> BSH;
        int pos = base[b] + atomicAdd(&cnt[b], 1);
        part[pos] = src | ((dst & 255) << 16);
    }
}

// one block per bucket: per-node degree count, LDS scan -> off[], place, flush
__global__ __launch_bounds__(256) void bucket_fill(
    const int* __restrict__ boff, const int* __restrict__ part,
    int* __restrict__ csr, int* __restrict__ off, int n)
{
    __shared__ int sm[256];
    __shared__ int cur[256];
    __shared__ int slice[12544];
    const int t = threadIdx.x;
    const int b = blockIdx.x;
    const int n0 = b << BSH;
    const int nodes = min(256, n - n0);
    const int off0 = boff[b];
    const int sz = boff[b + 1] - off0;

    cur[t] = 0;
    __syncthreads();
    for (int i = t; i < sz; i += 256)
        atomicAdd(&cur[(part[off0 + i] >> 16) & 255], 1);
    __syncthreads();
    int v = cur[t];
    sm[t] = v;
    __syncthreads();
    for (int d = 1; d < 256; d <<= 1) {
        int x = (t >= d) ? sm[t - d] : 0;
        __syncthreads();
        sm[t] += x;
        __syncthreads();
    }
    const int excl = sm[t] - v;
    if (t < nodes) off[n0 + t] = off0 + excl;
    if (t == nodes - 1) off[n0 + nodes] = off0 + sz;
    cur[t] = excl;
    __syncthreads();

    if (sz <= 12544) {
        for (int i = t; i < sz; i += 256) {
            int p  = part[off0 + i];
            int dl = (p >> 16) & 255;
            int pos = atomicAdd(&cur[dl], 1);
            slice[pos] = p & 0xFFFF;
        }
        __syncthreads();
        for (int i = t; i < sz; i += 256)
            csr[off0 + i] = slice[i];
    } else {                                     // fallback (shouldn't trigger)
        for (int i = t; i < sz; i += 256) {
            int p  = part[off0 + i];
            int dl = (p >> 16) & 255;
            int pos = atomicAdd(&cur[dl], 1);
            csr[off0 + pos] = p & 0xFFFF;
        }
    }
}

// ---------------- layer-1 MFMA GEMM (fp32 A, in-register cvt) --------------
__global__ __launch_bounds__(256) void gemm1_mfma(
    const float* __restrict__ A, const __half* __restrict__ Wt, // [128][128]
    __half* __restrict__ Hout, const float* __restrict__ a_s,
    const float* __restrict__ a_d, float* __restrict__ alS,
    float* __restrict__ alD, int nrows)
{
    constexpr int N = 128, NT = 8, WR = 136;
    __shared__ _Float16 hst[4][16 * WR];

    const int t = threadIdx.x, w = t >> 6, l = t & 63;
    const int q = l >> 4, n = l & 15;
    const int node0 = blockIdx.x * 64;
    const int row_base = node0 + w * 16;

    f32x4 acc[NT];
#pragma unroll
    for (int ct = 0; ct < NT; ct++) acc[ct] = (f32x4){0.f, 0.f, 0.f, 0.f};

    int arow = row_base + n; if (arow >= nrows) arow = nrows - 1;
    const float* Ap = A + (size_t)arow * 128 + q * 8;
#pragma unroll
    for (int ks = 0; ks < 4; ks++) {
        float4 va = *(const float4*)(Ap + ks * 32);
        float4 vb = *(const float4*)(Ap + ks * 32 + 4);
        f16x8 a = { (_Float16)va.x, (_Float16)va.y, (_Float16)va.z, (_Float16)va.w,
                    (_Float16)vb.x, (_Float16)vb.y, (_Float16)vb.z, (_Float16)vb.w };
#pragma unroll
        for (int ct = 0; ct < NT; ct++) {
            f16x8 bb = *(const f16x8*)&Wt[(ct * 16 + n) * 128 + ks * 32 + q * 8];
            acc[ct] = __builtin_amdgcn_mfma_f32_16x16x32_f16(a, bb, acc[ct], 0, 0, 0);
        }
    }

    float asv[NT], adv[NT];
#pragma unroll
    for (int ct = 0; ct < NT; ct++) {
        asv[ct] = a_s[ct * 16 + n];
        adv[ct] = a_d[ct * 16 + n];
    }
#pragma unroll
    for (int r = 0; r < 4; r++) {
        int grow = row_base + q * 4 + r;
        float s0 = 0.f, d0 = 0.f, s1 = 0.f, d1 = 0.f;
#pragma unroll
        for (int ct = 0; ct < NT; ct++) {
            float v = acc[ct][r];
            float ps = v * asv[ct], pd = v * adv[ct];
            if (ct >= 4) { s1 += ps; d1 += pd; }
            else         { s0 += ps; d0 += pd; }
        }
#pragma unroll
        for (int m = 1; m < 16; m <<= 1) {
            s0 += __shfl_xor(s0, m); d0 += __shfl_xor(d0, m);
            s1 += __shfl_xor(s1, m); d1 += __shfl_xor(d1, m);
        }
        if (n == 0 && grow < nrows) {
            alS[grow * 2] = s0;     alD[grow * 2] = d0;
            alS[grow * 2 + 1] = s1; alD[grow * 2 + 1] = d1;
        }
    }

#pragma unroll
    for (int ct = 0; ct < NT; ct++)
#pragma unroll
        for (int r = 0; r < 4; r++)
            hst[w][(q * 4 + r) * WR + ct * 16 + n] = (_Float16)acc[ct][r];
    __syncthreads();
    {
        int row = l >> 2, c = l & 3;
        int grow = row_base + row;
        if (grow < nrows) {
#pragma unroll
            for (int i = 0; i < 4; i++) {
                float4 v = *(float4*)&hst[w][row * WR + c * 32 + i * 8];
                *(float4*)&Hout[(size_t)grow * N + c * 32 + i * 8] = v;
            }
        }
    }
}

// ---------------- fused gather (H=2) + next-layer GEMM ---------------------
// Per block: 16 nodes. Gather h -> act rows (LDS, fp16, bias+ELU applied),
// then act(16x128) @ Wt^T via MFMA (B-fragments read from global/L2).
template<int OUTN>
__global__ __launch_bounds__(256) void gat_gather_gemm(
    const int* __restrict__ off, const int* __restrict__ csr,
    const __half* __restrict__ h, const float* __restrict__ alS,
    const float* __restrict__ alD, const float* __restrict__ bias,
    const __half* __restrict__ Wt, const float* __restrict__ a_s,
    const float* __restrict__ a_d, __half* __restrict__ Hout,
    float* __restrict__ alSo, float* __restrict__ alDo, int n)
{
    constexpr int H = 2, HF = 128, WR = 136;
    constexpr int CTW = OUTN / 64;        // col-tiles per wave
    constexpr int CPW = OUTN / 4;         // cols per wave
    __shared__ _Float16 actT[16 * WR];    // act rows; reused for out staging
    __shared__ float red_s[4][16], red_d[4][16];

    const int t = threadIdx.x;
    const int node0 = blockIdx.x * 16;

    // ---- gather ----
    const int l = t & 15;
    const int node = node0 + (t >> 4);
    const bool valid = node < n;
    const int c0 = l * 8;
    const int head = c0 >> 6;
    const int nodec = valid ? node : (n - 1);
    const float ad = alD[nodec * H + head];
    int s0 = 0, s1 = 1;
    if (valid) { s0 = off[node]; s1 = off[node + 1]; }
    const int last = s1 - 1;
    float a0 = 0.f, a1 = 0.f, a2 = 0.f, a3 = 0.f;
    float a4 = 0.f, a5 = 0.f, a6 = 0.f, a7 = 0.f, wsum = 0.f;

    float  as[4];
    float4 v[4];
    {
        int srcs[4];
#pragma unroll
        for (int k = 0; k < 4; k++) {
            int j = s0 + k;
            srcs[k] = csr[j <= last ? j : last];
        }
#pragma unroll
        for (int k = 0; k < 4; k++) {
            as[k] = alS[srcs[k] * H + head];
            v[k]  = *(const float4*)&h[(size_t)srcs[k] * HF + c0];
        }
    }
    for (int j = s0; j < s1; j += 4) {
        int nsrc[4];
#pragma unroll
        for (int k = 0; k < 4; k++) {
            int jj = j + 4 + k;
            nsrc[k] = csr[jj <= last ? jj : last];
        }
        float  nas[4];
        float4 nv[4];
#pragma unroll
        for (int k = 0; k < 4; k++) {
            nas[k] = alS[nsrc[k] * H + head];
            nv[k]  = *(const float4*)&h[(size_t)nsrc[k] * HF + c0];
        }
#pragma unroll
        for (int k = 0; k < 4; k++) {
            float s = as[k] + ad;
            s = s > 0.f ? s : 0.2f * s;     // leaky_relu(0.2)
            float w = __expf(s);
            w = (j + k <= last) ? w : 0.f;
            const __half2* hp = (const __half2*)&v[k];
            float2 f0 = __half22float2(hp[0]);
            float2 f1 = __half22float2(hp[1]);
            float2 f2 = __half22float2(hp[2]);
            float2 f3 = __half22float2(hp[3]);
            a0 = fmaf(w, f0.x, a0); a1 = fmaf(w, f0.y, a1);
            a2 = fmaf(w, f1.x, a2); a3 = fmaf(w, f1.y, a3);
            a4 = fmaf(w, f2.x, a4); a5 = fmaf(w, f2.y, a5);
            a6 = fmaf(w, f3.x, a6); a7 = fmaf(w, f3.y, a7);
            wsum += w;
        }
#pragma unroll
        for (int k = 0; k < 4; k++) { as[k] = nas[k]; v[k] = nv[k]; }
    }
    {
        const float inv = 1.f / (wsum + 1e-16f);
        float4 b0 = *(const float4*)&bias[c0];
        float4 b1 = *(const float4*)&bias[c0 + 4];
        float o[8];
        o[0] = ELU(fmaf(a0, inv, b0.x));
        o[1] = ELU(fmaf(a1, inv, b0.y));
        o[2] = ELU(fmaf(a2, inv, b0.z));
        o[3] = ELU(fmaf(a3, inv, b0.w));
        o[4] = ELU(fmaf(a4, inv, b1.x));
        o[5] = ELU(fmaf(a5, inv, b1.y));
        o[6] = ELU(fmaf(a6, inv, b1.z));
        o[7] = ELU(fmaf(a7, inv, b1.w));
        __half2 p[4];
#pragma unroll
        for (int k = 0; k < 4; k++) p[k] = __floats2half2_rn(o[2 * k], o[2 * k + 1]);
        *(float4*)&actT[(t >> 4) * WR + l * 8] = *(float4*)p;
    }
    __syncthreads();

    // ---- GEMM: D[node][col] = act @ Wt^T (B from global/L2) ----
    const int w = t >> 6, l64 = t & 63, q = l64 >> 4, nn = l64 & 15;
    f32x4 acc[CTW];
#pragma unroll
    for (int ct = 0; ct < CTW; ct++) acc[ct] = (f32x4){0.f, 0.f, 0.f, 0.f};
#pragma unroll
    for (int ks = 0; ks < 4; ks++) {
        f16x8 a = *(const f16x8*)&actT[nn * WR + ks * 32 + q * 8];
#pragma unroll
        for (int ct = 0; ct < CTW; ct++) {
            f16x8 bb = *(const f16x8*)&Wt[(size_t)(w * CPW + ct * 16 + nn) * 128 + ks * 32 + q * 8];
            acc[ct] = __builtin_amdgcn_mfma_f32_16x16x32_f16(a, bb, acc[ct], 0, 0, 0);
        }
    }

    // alS/alD partials: reduce over this wave's cols, then across waves (LDS)
    float asv[CTW], adv[CTW];
#pragma unroll
    for (int ct = 0; ct < CTW; ct++) {
        asv[ct] = a_s[w * CPW + ct * 16 + nn];
        adv[ct] = a_d[w * CPW + ct * 16 + nn];
    }
#pragma unroll
    for (int r = 0; r < 4; r++) {
        float s = 0.f, d = 0.f;
#pragma unroll
        for (int ct = 0; ct < CTW; ct++) {
            float vv = acc[ct][r];
            s = fmaf(vv, asv[ct], s);
            d = fmaf(vv, adv[ct], d);
        }
#pragma unroll
        for (int m = 1; m < 16; m <<= 1) {
            s += __shfl_xor(s, m);
            d += __shfl_xor(d, m);
        }
        if (nn == 0) { red_s[w][q * 4 + r] = s; red_d[w][q * 4 + r] = d; }
    }
    __syncthreads();

    // stage output into actT (reuse) + combine alS across waves
#pragma unroll
    for (int ct = 0; ct < CTW; ct++)
#pragma unroll
        for (int r = 0; r < 4; r++)
            actT[(q * 4 + r) * WR + w * CPW + ct * 16 + nn] = (_Float16)acc[ct][r];
    if (OUTN == 128) {
        if (t < 32) {
            int m = t & 15, hh = t >> 4;
            int grow = node0 + m;
            if (grow < n) {
                alSo[grow * 2 + hh] = red_s[2 * hh][m] + red_s[2 * hh + 1][m];
                alDo[grow * 2 + hh] = red_d[2 * hh][m] + red_d[2 * hh + 1][m];
            }
        }
    } else {
        if (t < 16) {
            int grow = node0 + t;
            if (grow < n) {
                alSo[grow] = red_s[0][t] + red_s[1][t] + red_s[2][t] + red_s[3][t];
                alDo[grow] = red_d[0][t] + red_d[1][t] + red_d[2][t] + red_d[3][t];
            }
        }
    }
    __syncthreads();

    // coalesced Hout store
    if (OUTN == 128) {
        int row = t >> 4, c = t & 15;
        int grow = node0 + row;
        if (grow < n)
            *(float4*)&Hout[(size_t)grow * 128 + c * 8] = *(float4*)&actT[row * WR + c * 8];
    } else {
        if (t < 128) {
            int row = t >> 3, c = t & 7;
            int grow = node0 + row;
            if (grow < n)
                *(float4*)&Hout[(size_t)grow * 64 + c * 8] = *(float4*)&actT[row * WR + c * 8];
        }
    }
}

// ---------------- final gather (H=1) -> fp32 out ---------------------------
__global__ __launch_bounds__(256) void gat_gather_out(
    const int* __restrict__ off, const int* __restrict__ csr,
    const __half* __restrict__ h, const float* __restrict__ alS,
    const float* __restrict__ alD, const float* __restrict__ b,
    float* __restrict__ out, int n)
{
    constexpr int HF = 64, LPN = 8, NPB = 32;
    const int l    = threadIdx.x % LPN;
    const int node = blockIdx.x * NPB + threadIdx.x / LPN;
    if (node >= n) return;
    const int c0   = l * 8;
    const float ad = alD[node];

    const int s0 = off[node], s1 = off[node + 1];
    const int last = s1 - 1;
    float a0 = 0.f, a1 = 0.f, a2 = 0.f, a3 = 0.f;
    float a4 = 0.f, a5 = 0.f, a6 = 0.f, a7 = 0.f, wsum = 0.f;

    float  as[4];
    float4 v[4];
    {
        int srcs[4];
#pragma unroll
        for (int k = 0; k < 4; k++) {
            int j = s0 + k;
            srcs[k] = csr[j <= last ? j : last];
        }
#pragma unroll
        for (int k = 0; k < 4; k++) {
            as[k] = alS[srcs[k]];
            v[k]  = *(const float4*)&h[(size_t)srcs[k] * HF + c0];
        }
    }
    for (int j = s0; j < s1; j += 4) {
        int nsrc[4];
#pragma unroll
        for (int k = 0; k < 4; k++) {
            int jj = j + 4 + k;
            nsrc[k] = csr[jj <= last ? jj : last];
        }
        float  nas[4];
        float4 nv[4];
#pragma unroll
        for (int k = 0; k < 4; k++) {
            nas[k] = alS[nsrc[k]];
            nv[k]  = *(const float4*)&h[(size_t)nsrc[k] * HF + c0];
        }
#pragma unroll
        for (int k = 0; k < 4; k++) {
            float s = as[k] + ad;
            s = s > 0.f ? s : 0.2f * s;
            float w = __expf(s);
            w = (j + k <= last) ? w : 0.f;
            const __half2* hp = (const __half2*)&v[k];
            float2 f0 = __half22float2(hp[0]);
            float2 f1 = __half22float2(hp[1]);
            float2 f2 = __half22float2(hp[2]);
            float2 f3 = __half22float2(hp[3]);
            a0 = fmaf(w, f0.x, a0); a1 = fmaf(w, f0.y, a1);
            a2 = fmaf(w, f1.x, a2); a3 = fmaf(w, f1.y, a3);
            a4 = fmaf(w, f2.x, a4); a5 = fmaf(w, f2.y, a5);
            a6 = fmaf(w, f3.x, a6); a7 = fmaf(w, f3.y, a7);
            wsum += w;
        }
#pragma unroll
        for (int k = 0; k < 4; k++) { as[k] = nas[k]; v[k] = nv[k]; }
    }

    const float inv = 1.f / (wsum + 1e-16f);
    float4 b0 = *(const float4*)&b[c0];
    float4 b1 = *(const float4*)&b[c0 + 4];
    float4 o0, o1;
    o0.x = ELU(fmaf(a0, inv, b0.x));
    o0.y = ELU(fmaf(a1, inv, b0.y));
    o0.z = ELU(fmaf(a2, inv, b0.z));
    o0.w = ELU(fmaf(a3, inv, b0.w));
    o1.x = ELU(fmaf(a4, inv, b1.x));
    o1.y = ELU(fmaf(a5, inv, b1.y));
    o1.z = ELU(fmaf(a6, inv, b1.z));
    o1.w = ELU(fmaf(a7, inv, b1.w));
    *(float4*)&out[(size_t)node * HF + c0]     = o0;
    *(float4*)&out[(size_t)node * HF + c0 + 4] = o1;
}

extern "C" void kernel_launch(void* const* d_in, const int* in_sizes, int n_in,
                              void* d_out, int out_size, void* d_ws, size_t ws_size,
                              hipStream_t stream)
{
    const float* x   = (const float*)d_in[0];
    const float* W1  = (const float*)d_in[1];
    const float* as1 = (const float*)d_in[2];
    const float* ad1 = (const float*)d_in[3];
    const float* b1  = (const float*)d_in[4];
    const float* W2  = (const float*)d_in[5];
    const float* as2 = (const float*)d_in[6];
    const float* ad2 = (const float*)d_in[7];
    const float* b2  = (const float*)d_in[8];
    const float* W3  = (const float*)d_in[9];
    const float* as3 = (const float*)d_in[10];
    const float* ad3 = (const float*)d_in[11];
    const float* b3  = (const float*)d_in[12];
    const int*   ei  = (const int*)d_in[13];
    float* out = (float*)d_out;

    const int N_   = in_sizes[0] / 128;     // 50000
    const int E_   = in_sizes[13] / 2;      // 1600000
    const int Etot = E_ + N_;
    const int NB   = (N_ + 255) >> BSH;     // 196 buckets
    const int HB   = (E_ + 8191) / 8192;    // 196 hist blocks

    char* ws = (char*)d_ws;
    size_t o = 0;
    auto alloc = [&](size_t bytes) { void* p = ws + o; o += (bytes + 255) & ~255ull; return p; };
    __half* h1    = (__half*)alloc((size_t)N_ * 128 * 2);
    __half* h2    = (__half*)alloc((size_t)N_ * 128 * 2);
    __half* h3    = (__half*)alloc((size_t)N_ * 64 * 2);
    __half* Wt1   = (__half*)alloc((size_t)128 * 128 * 2);
    __half* Wt2   = (__half*)alloc((size_t)128 * 128 * 2);
    __half* Wt3   = (__half*)alloc((size_t)64 * 128 * 2);
    float* alSa   = (float*)alloc((size_t)N_ * 2 * 4);
    float* alDa   = (float*)alloc((size_t)N_ * 2 * 4);
    float* alSb   = (float*)alloc((size_t)N_ * 2 * 4);
    float* alDb   = (float*)alloc((size_t)N_ * 2 * 4);
    int*   offb   = (int*)alloc((size_t)(N_ + 1) * 4);
    int*   bhrows = (int*)alloc((size_t)HB * 256 * 4);
    int*   boff   = (int*)alloc((size_t)257 * 4);
    int*   bcur   = (int*)alloc((size_t)256 * 4);
    int*   part   = (int*)alloc((size_t)Etot * 4);
    int*   csr    = (int*)alloc((size_t)Etot * 4);

    const dim3 blk(256);

    // ---- phase0 + CSR build ----
    phase0<<<160 + HB, blk, 0, stream>>>(W1, Wt1, W2, Wt2, W3, Wt3, ei, bhrows, E_, HB);
    bucket_scan<<<1, blk, 0, stream>>>(bhrows, HB, boff, bcur, N_, NB);
    edge_partition<<<(Etot + 2047) / 2048, blk, 0, stream>>>(ei, bcur, part, E_, Etot);
    bucket_fill<<<NB, blk, 0, stream>>>(boff, part, csr, offb, N_);

    // ---- layer pipeline ----
    gemm1_mfma<<<(N_ + 63) / 64, blk, 0, stream>>>(x, Wt1, h1, as1, ad1, alSa, alDa, N_);
    gat_gather_gemm<128><<<(N_ + 15) / 16, blk, 0, stream>>>(
        offb, csr, h1, alSa, alDa, b1, Wt2, as2, ad2, h2, alSb, alDb, N_);
    gat_gather_gemm<64><<<(N_ + 15) / 16, blk, 0, stream>>>(
        offb, csr, h2, alSb, alDb, b2, Wt3, as3, ad3, h3, alSa, alDa, N_);
    gat_gather_out<<<(N_ + 31) / 32, blk, 0, stream>>>(
        offb, csr, h3, alSa, alDa, b3, out, N_);
}

// Round 13
// 360.372 us; speedup vs baseline: 1.0294x; 1.0294x over previous
//
#include <hip/hip_runtime.h>
#include <hip/hip_bf16.h>
#include <hip/hip_fp16.h>

// ---------------------------------------------------------------------------
// 3-layer GAT encoder. N=50000, E=1600000 (+N self loops), H=2 (layers 1-2),
// F=64 per head, F_IN=128.
// R1: scatter+atomics -> CSR-by-dst + register gather.
// R2: CSR build via LDS-aggregated counting sort.   R3: al fused into GEMM.
// R4: h fp16.  R5/R6: fast scan; bucket histogram.  R7: MFMA GEMM.
// R8 FAILED (cooperative CSR).  R10: GEMM2/3 fused into gather epilogues.
// R11 FAILED (global-W MFMA reads: 66->75us; 2048-chunk partition: +8us).
// R12: revert to R10 (LDS-staged W everywhere) + single-pass deterministic
//      edge partition: per-block write bases precomputed from phase0's
//      histogram rows (scan_bases); self-loops placed at bucket tails with
//      coalesced writes; zero global atomics in the whole CSR build.
// ---------------------------------------------------------------------------

#define ELU(x) ((x) > 0.f ? (x) : (__expf(x) - 1.f))
#define BSH 8                       // 256 nodes per bucket
#define CHK 4096                    // edges per histogram/partition block

typedef _Float16 f16x8 __attribute__((ext_vector_type(8)));
typedef float    f32x4 __attribute__((ext_vector_type(4)));

// ---------------- phase0: Wt builds + per-block dst histogram rows ---------
__global__ __launch_bounds__(256) void phase0(
    const float* __restrict__ W1, __half* __restrict__ Wt1,
    const float* __restrict__ W2, __half* __restrict__ Wt2,
    const float* __restrict__ W3, __half* __restrict__ Wt3,
    const int* __restrict__ ei, int* __restrict__ bhist_rows, int E_)
{
    const int t = threadIdx.x;
    const int b = blockIdx.x;
    if (b < 160) {                                   // Wt[n][k] = (h) W[k][n]
        const float* W; __half* Wt; int N, base;
        if (b < 64)       { W = W1; Wt = Wt1; N = 128; base = b; }
        else if (b < 128) { W = W2; Wt = Wt2; N = 128; base = b - 64; }
        else              { W = W3; Wt = Wt3; N = 64;  base = b - 128; }
        int idx = base * 256 + t;
        if (idx < N * 128) {
            int nn = idx >> 7, k = idx & 127;
            Wt[idx] = __float2half(W[k * N + nn]);
        }
    } else {                                         // dst histogram row
        __shared__ int cnt[256];
        int hb = b - 160;
        cnt[t] = 0;
        __syncthreads();
        const int e0 = hb * CHK;
        for (int i = t; i < CHK; i += 256) {
            int e = e0 + i;
            if (e >= E_) break;
            atomicAdd(&cnt[ei[E_ + e] >> BSH], 1);
        }
        __syncthreads();
        bhist_rows[hb * 256 + t] = cnt[t];
    }
}

// one block: column-sum hist rows + self loops, scan -> boff
__global__ __launch_bounds__(256) void bucket_scan(
    const int* __restrict__ bhist_rows, int HB, int* __restrict__ boff,
    int n, int NB)
{
    __shared__ int sm[256];
    const int t = threadIdx.x;
    int v = 0;
    for (int r = 0; r < HB; r++) v += bhist_rows[r * 256 + t];
    int nodes = n - (t << BSH);
    nodes = nodes < 0 ? 0 : (nodes > 256 ? 256 : nodes);
    v = (t < NB) ? (v + nodes) : 0;              // + self loops
    sm[t] = v;
    __syncthreads();
    for (int d = 1; d < 256; d <<= 1) {
        int x = (t >= d) ? sm[t - d] : 0;
        __syncthreads();
        sm[t] += x;
        __syncthreads();
    }
    if (t < NB) boff[t + 1] = sm[t];
    if (t == 0) boff[0] = 0;
}

// one block per bucket: column-scan hist rows -> per-(block,bucket) bases;
// write self-loop part entries at bucket tail (coalesced). HB <= 512.
__global__ __launch_bounds__(256) void scan_bases(
    const int* __restrict__ bhist_rows, const int* __restrict__ boff,
    int* __restrict__ bases, int* __restrict__ part, int HB, int n)
{
    __shared__ int col[512];
    __shared__ int psum[256];
    const int t = threadIdx.x;
    const int b = blockIdx.x;                    // bucket
    col[t]       = (t < HB)       ? bhist_rows[t * 256 + b]         : 0;
    col[t + 256] = (t + 256 < HB) ? bhist_rows[(t + 256) * 256 + b] : 0;
    __syncthreads();
    int s = col[2 * t] + col[2 * t + 1];
    psum[t] = s;
    __syncthreads();
    for (int d = 1; d < 256; d <<= 1) {
        int x = (t >= d) ? psum[t - d] : 0;
        __syncthreads();
        psum[t] += x;
        __syncthreads();
    }
    const int base0 = boff[b];
    int e0 = base0 + psum[t] - s;                // exclusive prefix of pair
    int e1 = e0 + col[2 * t];
    if (2 * t     < HB) bases[b * HB + 2 * t]     = e0;
    if (2 * t + 1 < HB) bases[b * HB + 2 * t + 1] = e1;
    // self loops at end of bucket
    const int n0 = b << BSH;
    const int nodes = min(256, n - n0);
    const int sl0 = boff[b + 1] - nodes;
    if (t < nodes) part[sl0 + t] = (n0 + t) | (t << 16);
}

// single-pass partition: deterministic bases, LDS-local cursors only.
// packed entry: src (bits 0..15) | dst_local (bits 16..23)
__global__ __launch_bounds__(256) void edge_partition(
    const int* __restrict__ ei, const int* __restrict__ bases,
    int* __restrict__ part, int E_, int HB, int NB)
{
    __shared__ int cnt[256];
    __shared__ int sbase[256];
    const int t = threadIdx.x;
    const int hb = blockIdx.x;
    cnt[t] = 0;
    sbase[t] = (t < NB) ? bases[t * HB + hb] : 0;
    __syncthreads();
    const int e0 = hb * CHK;
    for (int i = t; i < CHK; i += 256) {
        int e = e0 + i;
        if (e >= E_) break;
        int src = ei[e], dst = ei[E_ + e];
        int b = dst >> BSH;
        int pos = sbase[b] + atomicAdd(&cnt[b], 1);
        part[pos] = src | ((dst & 255) << 16);
    }
}

// one block per bucket: per-node degree count, LDS scan -> off[], place, flush
__global__ __launch_bounds__(256) void bucket_fill(
    const int* __restrict__ boff, const int* __restrict__ part,
    int* __restrict__ csr, int* __restrict__ off, int n)
{
    __shared__ int sm[256];
    __shared__ int cur[256];
    __shared__ int slice[12544];
    const int t = threadIdx.x;
    const int b = blockIdx.x;
    const int n0 = b << BSH;
    const int nodes = min(256, n - n0);
    const int off0 = boff[b];
    const int sz = boff[b + 1] - off0;

    cur[t] = 0;
    __syncthreads();
    for (int i = t; i < sz; i += 256)
        atomicAdd(&cur[(part[off0 + i] >> 16) & 255], 1);
    __syncthreads();
    int v = cur[t];
    sm[t] = v;
    __syncthreads();
    for (int d = 1; d < 256; d <<= 1) {
        int x = (t >= d) ? sm[t - d] : 0;
        __syncthreads();
        sm[t] += x;
        __syncthreads();
    }
    const int excl = sm[t] - v;
    if (t < nodes) off[n0 + t] = off0 + excl;
    if (t == nodes - 1) off[n0 + nodes] = off0 + sz;
    cur[t] = excl;
    __syncthreads();

    if (sz <= 12544) {
        for (int i = t; i < sz; i += 256) {
            int p  = part[off0 + i];
            int dl = (p >> 16) & 255;
            int pos = atomicAdd(&cur[dl], 1);
            slice[pos] = p & 0xFFFF;
        }
        __syncthreads();
        for (int i = t; i < sz; i += 256)
            csr[off0 + i] = slice[i];
    } else {                                     // fallback (shouldn't trigger)
        for (int i = t; i < sz; i += 256) {
            int p  = part[off0 + i];
            int dl = (p >> 16) & 255;
            int pos = atomicAdd(&cur[dl], 1);
            csr[off0 + pos] = p & 0xFFFF;
        }
    }
}

// ---------------- layer-1 MFMA GEMM (fp32 A, in-register cvt; LDS W) -------
__global__ __launch_bounds__(256) void gemm1_mfma(
    const float* __restrict__ A, const __half* __restrict__ Wt, // [128][128]
    __half* __restrict__ Hout, const float* __restrict__ a_s,
    const float* __restrict__ a_d, float* __restrict__ alS,
    float* __restrict__ alD, int nrows)
{
    constexpr int N = 128, NT = 8, WR = 136;
    __shared__ _Float16 wt[N * WR];
    __shared__ _Float16 hst[4][16 * WR];

    const int t = threadIdx.x, w = t >> 6, l = t & 63;
    const int q = l >> 4, n = l & 15;
    const int node0 = blockIdx.x * 64;
    const int row_base = node0 + w * 16;

    for (int i = t; i < N * 16; i += 256) {
        int r = i >> 4, c = i & 15;
        float4 v = *(const float4*)&Wt[r * 128 + c * 8];
        *(float4*)&wt[r * WR + c * 8] = v;
    }
    __syncthreads();

    f32x4 acc[NT];
#pragma unroll
    for (int ct = 0; ct < NT; ct++) acc[ct] = (f32x4){0.f, 0.f, 0.f, 0.f};

    int arow = row_base + n; if (arow >= nrows) arow = nrows - 1;
    const float* Ap = A + (size_t)arow * 128 + q * 8;
#pragma unroll
    for (int ks = 0; ks < 4; ks++) {
        float4 va = *(const float4*)(Ap + ks * 32);
        float4 vb = *(const float4*)(Ap + ks * 32 + 4);
        f16x8 a = { (_Float16)va.x, (_Float16)va.y, (_Float16)va.z, (_Float16)va.w,
                    (_Float16)vb.x, (_Float16)vb.y, (_Float16)vb.z, (_Float16)vb.w };
#pragma unroll
        for (int ct = 0; ct < NT; ct++) {
            f16x8 bb = *(const f16x8*)&wt[(ct * 16 + n) * WR + ks * 32 + q * 8];
            acc[ct] = __builtin_amdgcn_mfma_f32_16x16x32_f16(a, bb, acc[ct], 0, 0, 0);
        }
    }

    float asv[NT], adv[NT];
#pragma unroll
    for (int ct = 0; ct < NT; ct++) {
        asv[ct] = a_s[ct * 16 + n];
        adv[ct] = a_d[ct * 16 + n];
    }
#pragma unroll
    for (int r = 0; r < 4; r++) {
        int grow = row_base + q * 4 + r;
        float s0 = 0.f, d0 = 0.f, s1 = 0.f, d1 = 0.f;
#pragma unroll
        for (int ct = 0; ct < NT; ct++) {
            float v = acc[ct][r];
            float ps = v * asv[ct], pd = v * adv[ct];
            if (ct >= 4) { s1 += ps; d1 += pd; }
            else         { s0 += ps; d0 += pd; }
        }
#pragma unroll
        for (int m = 1; m < 16; m <<= 1) {
            s0 += __shfl_xor(s0, m); d0 += __shfl_xor(d0, m);
            s1 += __shfl_xor(s1, m); d1 += __shfl_xor(d1, m);
        }
        if (n == 0 && grow < nrows) {
            alS[grow * 2] = s0;     alD[grow * 2] = d0;
            alS[grow * 2 + 1] = s1; alD[grow * 2 + 1] = d1;
        }
    }

#pragma unroll
    for (int ct = 0; ct < NT; ct++)
#pragma unroll
        for (int r = 0; r < 4; r++)
            hst[w][(q * 4 + r) * WR + ct * 16 + n] = (_Float16)acc[ct][r];
    __syncthreads();
    {
        int row = l >> 2, c = l & 3;
        int grow = row_base + row;
        if (grow < nrows) {
#pragma unroll
            for (int i = 0; i < 4; i++) {
                float4 v = *(float4*)&hst[w][row * WR + c * 32 + i * 8];
                *(float4*)&Hout[(size_t)grow * N + c * 32 + i * 8] = v;
            }
        }
    }
}

// ---------------- fused gather (H=2) + next-layer GEMM (LDS-staged W) ------
template<int OUTN>
__global__ __launch_bounds__(256) void gat_gather_gemm(
    const int* __restrict__ off, const int* __restrict__ csr,
    const __half* __restrict__ h, const float* __restrict__ alS,
    const float* __restrict__ alD, const float* __restrict__ bias,
    const __half* __restrict__ Wt, const float* __restrict__ a_s,
    const float* __restrict__ a_d, __half* __restrict__ Hout,
    float* __restrict__ alSo, float* __restrict__ alDo, int n)
{
    constexpr int H = 2, HF = 128, WR = 136;
    constexpr int CTW = OUTN / 64;        // col-tiles per wave
    constexpr int CPW = OUTN / 4;         // cols per wave
    __shared__ _Float16 wls[OUTN * WR];
    __shared__ _Float16 actT[16 * WR];    // act rows; reused for out staging
    __shared__ float red_s[4][16], red_d[4][16];

    const int t = threadIdx.x;
    const int node0 = blockIdx.x * 16;

    // stage Wt early (overlaps gather latency; synced before MFMA use)
    for (int i = t; i < OUTN * 16; i += 256) {
        int r = i >> 4, c = i & 15;
        float4 v = *(const float4*)&Wt[r * 128 + c * 8];
        *(float4*)&wls[r * WR + c * 8] = v;
    }

    // ---- gather ----
    const int l = t & 15;
    const int node = node0 + (t >> 4);
    const bool valid = node < n;
    const int c0 = l * 8;
    const int head = c0 >> 6;
    const int nodec = valid ? node : (n - 1);
    const float ad = alD[nodec * H + head];
    int s0 = 0, s1 = 1;
    if (valid) { s0 = off[node]; s1 = off[node + 1]; }
    const int last = s1 - 1;
    float a0 = 0.f, a1 = 0.f, a2 = 0.f, a3 = 0.f;
    float a4 = 0.f, a5 = 0.f, a6 = 0.f, a7 = 0.f, wsum = 0.f;

    float  as[4];
    float4 v[4];
    {
        int srcs[4];
#pragma unroll
        for (int k = 0; k < 4; k++) {
            int j = s0 + k;
            srcs[k] = csr[j <= last ? j : last];
        }
#pragma unroll
        for (int k = 0; k < 4; k++) {
            as[k] = alS[srcs[k] * H + head];
            v[k]  = *(const float4*)&h[(size_t)srcs[k] * HF + c0];
        }
    }
    for (int j = s0; j < s1; j += 4) {
        int nsrc[4];
#pragma unroll
        for (int k = 0; k < 4; k++) {
            int jj = j + 4 + k;
            nsrc[k] = csr[jj <= last ? jj : last];
        }
        float  nas[4];
        float4 nv[4];
#pragma unroll
        for (int k = 0; k < 4; k++) {
            nas[k] = alS[nsrc[k] * H + head];
            nv[k]  = *(const float4*)&h[(size_t)nsrc[k] * HF + c0];
        }
#pragma unroll
        for (int k = 0; k < 4; k++) {
            float s = as[k] + ad;
            s = s > 0.f ? s : 0.2f * s;     // leaky_relu(0.2)
            float w = __expf(s);
            w = (j + k <= last) ? w : 0.f;
            const __half2* hp = (const __half2*)&v[k];
            float2 f0 = __half22float2(hp[0]);
            float2 f1 = __half22float2(hp[1]);
            float2 f2 = __half22float2(hp[2]);
            float2 f3 = __half22float2(hp[3]);
            a0 = fmaf(w, f0.x, a0); a1 = fmaf(w, f0.y, a1);
            a2 = fmaf(w, f1.x, a2); a3 = fmaf(w, f1.y, a3);
            a4 = fmaf(w, f2.x, a4); a5 = fmaf(w, f2.y, a5);
            a6 = fmaf(w, f3.x, a6); a7 = fmaf(w, f3.y, a7);
            wsum += w;
        }
#pragma unroll
        for (int k = 0; k < 4; k++) { as[k] = nas[k]; v[k] = nv[k]; }
    }
    {
        const float inv = 1.f / (wsum + 1e-16f);
        float4 b0 = *(const float4*)&bias[c0];
        float4 b1 = *(const float4*)&bias[c0 + 4];
        float o[8];
        o[0] = ELU(fmaf(a0, inv, b0.x));
        o[1] = ELU(fmaf(a1, inv, b0.y));
        o[2] = ELU(fmaf(a2, inv, b0.z));
        o[3] = ELU(fmaf(a3, inv, b0.w));
        o[4] = ELU(fmaf(a4, inv, b1.x));
        o[5] = ELU(fmaf(a5, inv, b1.y));
        o[6] = ELU(fmaf(a6, inv, b1.z));
        o[7] = ELU(fmaf(a7, inv, b1.w));
        __half2 p[4];
#pragma unroll
        for (int k = 0; k < 4; k++) p[k] = __floats2half2_rn(o[2 * k], o[2 * k + 1]);
        *(float4*)&actT[(t >> 4) * WR + l * 8] = *(float4*)p;
    }
    __syncthreads();

    // ---- GEMM: D[node][col] = act @ Wt^T ----
    const int w = t >> 6, l64 = t & 63, q = l64 >> 4, nn = l64 & 15;
    f32x4 acc[CTW];
#pragma unroll
    for (int ct = 0; ct < CTW; ct++) acc[ct] = (f32x4){0.f, 0.f, 0.f, 0.f};
#pragma unroll
    for (int ks = 0; ks < 4; ks++) {
        f16x8 a = *(const f16x8*)&actT[nn * WR + ks * 32 + q * 8];
#pragma unroll
        for (int ct = 0; ct < CTW; ct++) {
            f16x8 bb = *(const f16x8*)&wls[(w * CPW + ct * 16 + nn) * WR + ks * 32 + q * 8];
            acc[ct] = __builtin_amdgcn_mfma_f32_16x16x32_f16(a, bb, acc[ct], 0, 0, 0);
        }
    }

    // alS/alD partials: reduce over this wave's cols, then across waves (LDS)
    float asv[CTW], adv[CTW];
#pragma unroll
    for (int ct = 0; ct < CTW; ct++) {
        asv[ct] = a_s[w * CPW + ct * 16 + nn];
        adv[ct] = a_d[w * CPW + ct * 16 + nn];
    }
#pragma unroll
    for (int r = 0; r < 4; r++) {
        float s = 0.f, d = 0.f;
#pragma unroll
        for (int ct = 0; ct < CTW; ct++) {
            float vv = acc[ct][r];
            s = fmaf(vv, asv[ct], s);
            d = fmaf(vv, adv[ct], d);
        }
#pragma unroll
        for (int m = 1; m < 16; m <<= 1) {
            s += __shfl_xor(s, m);
            d += __shfl_xor(d, m);
        }
        if (nn == 0) { red_s[w][q * 4 + r] = s; red_d[w][q * 4 + r] = d; }
    }
    __syncthreads();

    // stage output into actT (reuse) + combine alS across waves
#pragma unroll
    for (int ct = 0; ct < CTW; ct++)
#pragma unroll
        for (int r = 0; r < 4; r++)
            actT[(q * 4 + r) * WR + w * CPW + ct * 16 + nn] = (_Float16)acc[ct][r];
    if (OUTN == 128) {
        if (t < 32) {
            int m = t & 15, hh = t >> 4;
            int grow = node0 + m;
            if (grow < n) {
                alSo[grow * 2 + hh] = red_s[2 * hh][m] + red_s[2 * hh + 1][m];
                alDo[grow * 2 + hh] = red_d[2 * hh][m] + red_d[2 * hh + 1][m];
            }
        }
    } else {
        if (t < 16) {
            int grow = node0 + t;
            if (grow < n) {
                alSo[grow] = red_s[0][t] + red_s[1][t] + red_s[2][t] + red_s[3][t];
                alDo[grow] = red_d[0][t] + red_d[1][t] + red_d[2][t] + red_d[3][t];
            }
        }
    }
    __syncthreads();

    // coalesced Hout store
    if (OUTN == 128) {
        int row = t >> 4, c = t & 15;
        int grow = node0 + row;
        if (grow < n)
            *(float4*)&Hout[(size_t)grow * 128 + c * 8] = *(float4*)&actT[row * WR + c * 8];
    } else {
        if (t < 128) {
            int row = t >> 3, c = t & 7;
            int grow = node0 + row;
            if (grow < n)
                *(float4*)&Hout[(size_t)grow * 64 + c * 8] = *(float4*)&actT[row * WR + c * 8];
        }
    }
}

// ---------------- final gather (H=1) -> fp32 out ---------------------------
__global__ __launch_bounds__(256) void gat_gather_out(
    const int* __restrict__ off, const int* __restrict__ csr,
    const __half* __restrict__ h, const float* __restrict__ alS,
    const float* __restrict__ alD, const float* __restrict__ b,
    float* __restrict__ out, int n)
{
    constexpr int HF = 64, LPN = 8, NPB = 32;
    const int l    = threadIdx.x % LPN;
    const int node = blockIdx.x * NPB + threadIdx.x / LPN;
    if (node >= n) return;
    const int c0   = l * 8;
    const float ad = alD[node];

    const int s0 = off[node], s1 = off[node + 1];
    const int last = s1 - 1;
    float a0 = 0.f, a1 = 0.f, a2 = 0.f, a3 = 0.f;
    float a4 = 0.f, a5 = 0.f, a6 = 0.f, a7 = 0.f, wsum = 0.f;

    float  as[4];
    float4 v[4];
    {
        int srcs[4];
#pragma unroll
        for (int k = 0; k < 4; k++) {
            int j = s0 + k;
            srcs[k] = csr[j <= last ? j : last];
        }
#pragma unroll
        for (int k = 0; k < 4; k++) {
            as[k] = alS[srcs[k]];
            v[k]  = *(const float4*)&h[(size_t)srcs[k] * HF + c0];
        }
    }
    for (int j = s0; j < s1; j += 4) {
        int nsrc[4];
#pragma unroll
        for (int k = 0; k < 4; k++) {
            int jj = j + 4 + k;
            nsrc[k] = csr[jj <= last ? jj : last];
        }
        float  nas[4];
        float4 nv[4];
#pragma unroll
        for (int k = 0; k < 4; k++) {
            nas[k] = alS[nsrc[k]];
            nv[k]  = *(const float4*)&h[(size_t)nsrc[k] * HF + c0];
        }
#pragma unroll
        for (int k = 0; k < 4; k++) {
            float s = as[k] + ad;
            s = s > 0.f ? s : 0.2f * s;
            float w = __expf(s);
            w = (j + k <= last) ? w : 0.f;
            const __half2* hp = (const __half2*)&v[k];
            float2 f0 = __half22float2(hp[0]);
            float2 f1 = __half22float2(hp[1]);
            float2 f2 = __half22float2(hp[2]);
            float2 f3 = __half22float2(hp[3]);
            a0 = fmaf(w, f0.x, a0); a1 = fmaf(w, f0.y, a1);
            a2 = fmaf(w, f1.x, a2); a3 = fmaf(w, f1.y, a3);
            a4 = fmaf(w, f2.x, a4); a5 = fmaf(w, f2.y, a5);
            a6 = fmaf(w, f3.x, a6); a7 = fmaf(w, f3.y, a7);
            wsum += w;
        }
#pragma unroll
        for (int k = 0; k < 4; k++) { as[k] = nas[k]; v[k] = nv[k]; }
    }

    const float inv = 1.f / (wsum + 1e-16f);
    float4 b0 = *(const float4*)&b[c0];
    float4 b1 = *(const float4*)&b[c0 + 4];
    float4 o0, o1;
    o0.x = ELU(fmaf(a0, inv, b0.x));
    o0.y = ELU(fmaf(a1, inv, b0.y));
    o0.z = ELU(fmaf(a2, inv, b0.z));
    o0.w = ELU(fmaf(a3, inv, b0.w));
    o1.x = ELU(fmaf(a4, inv, b1.x));
    o1.y = ELU(fmaf(a5, inv, b1.y));
    o1.z = ELU(fmaf(a6, inv, b1.z));
    o1.w = ELU(fmaf(a7, inv, b1.w));
    *(float4*)&out[(size_t)node * HF + c0]     = o0;
    *(float4*)&out[(size_t)node * HF + c0 + 4] = o1;
}

extern "C" void kernel_launch(void* const* d_in, const int* in_sizes, int n_in,
                              void* d_out, int out_size, void* d_ws, size_t ws_size,
                              hipStream_t stream)
{
    const float* x   = (const float*)d_in[0];
    const float* W1  = (const float*)d_in[1];
    const float* as1 = (const float*)d_in[2];
    const float* ad1 = (const float*)d_in[3];
    const float* b1  = (const float*)d_in[4];
    const float* W2  = (const float*)d_in[5];
    const float* as2 = (const float*)d_in[6];
    const float* ad2 = (const float*)d_in[7];
    const float* b2  = (const float*)d_in[8];
    const float* W3  = (const float*)d_in[9];
    const float* as3 = (const float*)d_in[10];
    const float* ad3 = (const float*)d_in[11];
    const float* b3  = (const float*)d_in[12];
    const int*   ei  = (const int*)d_in[13];
    float* out = (float*)d_out;

    const int N_   = in_sizes[0] / 128;     // 50000
    const int E_   = in_sizes[13] / 2;      // 1600000
    const int Etot = E_ + N_;
    const int NB   = (N_ + 255) >> BSH;     // 196 buckets
    const int HB   = (E_ + CHK - 1) / CHK;  // 391 hist/partition blocks

    char* ws = (char*)d_ws;
    size_t o = 0;
    auto alloc = [&](size_t bytes) { void* p = ws + o; o += (bytes + 255) & ~255ull; return p; };
    __half* h1    = (__half*)alloc((size_t)N_ * 128 * 2);
    __half* h2    = (__half*)alloc((size_t)N_ * 128 * 2);
    __half* h3    = (__half*)alloc((size_t)N_ * 64 * 2);
    __half* Wt1   = (__half*)alloc((size_t)128 * 128 * 2);
    __half* Wt2   = (__half*)alloc((size_t)128 * 128 * 2);
    __half* Wt3   = (__half*)alloc((size_t)64 * 128 * 2);
    float* alSa   = (float*)alloc((size_t)N_ * 2 * 4);
    float* alDa   = (float*)alloc((size_t)N_ * 2 * 4);
    float* alSb   = (float*)alloc((size_t)N_ * 2 * 4);
    float* alDb   = (float*)alloc((size_t)N_ * 2 * 4);
    int*   offb   = (int*)alloc((size_t)(N_ + 1) * 4);
    int*   bhrows = (int*)alloc((size_t)HB * 256 * 4);
    int*   boff   = (int*)alloc((size_t)257 * 4);
    int*   bases  = (int*)alloc((size_t)256 * HB * 4);
    int*   part   = (int*)alloc((size_t)Etot * 4);
    int*   csr    = (int*)alloc((size_t)Etot * 4);

    const dim3 blk(256);

    // ---- phase0 + CSR build (no global atomics anywhere) ----
    phase0<<<160 + HB, blk, 0, stream>>>(W1, Wt1, W2, Wt2, W3, Wt3, ei, bhrows, E_);
    bucket_scan<<<1, blk, 0, stream>>>(bhrows, HB, boff, N_, NB);
    scan_bases<<<NB, blk, 0, stream>>>(bhrows, boff, bases, part, HB, N_);
    edge_partition<<<HB, blk, 0, stream>>>(ei, bases, part, E_, HB, NB);
    bucket_fill<<<NB, blk, 0, stream>>>(boff, part, csr, offb, N_);

    // ---- layer pipeline ----
    gemm1_mfma<<<(N_ + 63) / 64, blk, 0, stream>>>(x, Wt1, h1, as1, ad1, alSa, alDa, N_);
    gat_gather_gemm<128><<<(N_ + 15) / 16, blk, 0, stream>>>(
        offb, csr, h1, alSa, alDa, b1, Wt2, as2, ad2, h2, alSb, alDb, N_);
    gat_gather_gemm<64><<<(N_ + 15) / 16, blk, 0, stream>>>(
        offb, csr, h2, alSb, alDb, b2, Wt3, as3, ad3, h3, alSa, alDa, N_);
    gat_gather_out<<<(N_ + 31) / 32, blk, 0, stream>>>(
        offb, csr, h3, alSa, alDa, b3, out, N_);
}

// Round 14
// 338.406 us; speedup vs baseline: 1.0962x; 1.0649x over previous
//
#include <hip/hip_runtime.h>
#include <hip/hip_bf16.h>
#include <hip/hip_fp16.h>

// ---------------------------------------------------------------------------
// 3-layer GAT encoder. N=50000, E=1600000 (+N self loops), H=2 (layers 1-2),
// F=64 per head, F_IN=128.
// R1: scatter+atomics -> CSR-by-dst + register gather.
// R2: CSR build via LDS-aggregated counting sort.   R3: al fused into GEMM.
// R4: h fp16.  R7: MFMA GEMM.  R8 FAILED (cooperative CSR).
// R10: GEMM2/3 fused into gather epilogues (345us, best).
// R11 FAILED (global-W MFMA).  R12 partial (deterministic partition good,
//      CHK 4096 + extra dispatch bad: 360us).
// R13: R10 config + single-pass deterministic partition at CHK 8192 +
//      bucket_scan merged into scan_bases (8 dispatches, run-length kept).
// ---------------------------------------------------------------------------

#define ELU(x) ((x) > 0.f ? (x) : (__expf(x) - 1.f))
#define BSH 8                       // 256 nodes per bucket
#define CHK 8192                    // edges per histogram/partition block

typedef _Float16 f16x8 __attribute__((ext_vector_type(8)));
typedef float    f32x4 __attribute__((ext_vector_type(4)));

// ---------------- phase0: Wt builds + per-block dst histogram rows ---------
__global__ __launch_bounds__(256) void phase0(
    const float* __restrict__ W1, __half* __restrict__ Wt1,
    const float* __restrict__ W2, __half* __restrict__ Wt2,
    const float* __restrict__ W3, __half* __restrict__ Wt3,
    const int* __restrict__ ei, int* __restrict__ bhist_rows, int E_)
{
    const int t = threadIdx.x;
    const int b = blockIdx.x;
    if (b < 160) {                                   // Wt[n][k] = (h) W[k][n]
        const float* W; __half* Wt; int N, base;
        if (b < 64)       { W = W1; Wt = Wt1; N = 128; base = b; }
        else if (b < 128) { W = W2; Wt = Wt2; N = 128; base = b - 64; }
        else              { W = W3; Wt = Wt3; N = 64;  base = b - 128; }
        int idx = base * 256 + t;
        if (idx < N * 128) {
            int nn = idx >> 7, k = idx & 127;
            Wt[idx] = __float2half(W[k * N + nn]);
        }
    } else {                                         // dst histogram row
        __shared__ int cnt[256];
        int hb = b - 160;
        cnt[t] = 0;
        __syncthreads();
        const int e0 = hb * CHK;
        for (int i = t; i < CHK; i += 256) {
            int e = e0 + i;
            if (e >= E_) break;
            atomicAdd(&cnt[ei[E_ + e] >> BSH], 1);
        }
        __syncthreads();
        bhist_rows[hb * 256 + t] = cnt[t];
    }
}

// one block per bucket: (a) bucket totals + scan (block 0 writes boff),
// (b) column scan of this bucket -> per-partition-block bases,
// (c) self-loop part entries at bucket tail. HB <= 256.
__global__ __launch_bounds__(256) void scan_bases(
    const int* __restrict__ bhist_rows, int* __restrict__ boff,
    int* __restrict__ bases, int* __restrict__ part, int HB, int n, int NB)
{
    __shared__ int tot[256];
    __shared__ int col[256];
    const int t = threadIdx.x;
    const int b = blockIdx.x;                        // bucket

    // bucket totals (+ self loops), inclusive scan
    int v = 0;
    for (int r = 0; r < HB; r++) v += bhist_rows[r * 256 + t];
    int nodes_t = n - (t << BSH);
    nodes_t = nodes_t < 0 ? 0 : (nodes_t > 256 ? 256 : nodes_t);
    v = (t < NB) ? (v + nodes_t) : 0;
    tot[t] = v;
    __syncthreads();
    for (int d = 1; d < 256; d <<= 1) {
        int x = (t >= d) ? tot[t - d] : 0;
        __syncthreads();
        tot[t] += x;
        __syncthreads();
    }
    if (b == 0) {
        if (t < NB) boff[t + 1] = tot[t];
        if (t == 0) boff[0] = 0;
    }
    const int base0 = (b > 0) ? tot[b - 1] : 0;      // boff[b]
    const int bend  = tot[b];                        // boff[b+1]

    // column scan for this bucket -> bases
    int c = (t < HB) ? bhist_rows[t * 256 + b] : 0;
    col[t] = c;
    __syncthreads();
    for (int d = 1; d < 256; d <<= 1) {
        int x = (t >= d) ? col[t - d] : 0;
        __syncthreads();
        col[t] += x;
        __syncthreads();
    }
    if (t < HB) bases[b * HB + t] = base0 + col[t] - c;   // exclusive

    // self loops at bucket tail (coalesced)
    const int n0 = b << BSH;
    const int nodes = min(256, n - n0);
    const int sl0 = bend - nodes;
    if (t < nodes) part[sl0 + t] = (n0 + t) | (t << 16);
}

// single-pass partition: deterministic bases, LDS-local cursors only.
// packed entry: src (bits 0..15) | dst_local (bits 16..23)
__global__ __launch_bounds__(256) void edge_partition(
    const int* __restrict__ ei, const int* __restrict__ bases,
    int* __restrict__ part, int E_, int HB, int NB)
{
    __shared__ int cnt[256];
    __shared__ int sbase[256];
    const int t = threadIdx.x;
    const int hb = blockIdx.x;
    cnt[t] = 0;
    sbase[t] = (t < NB) ? bases[t * HB + hb] : 0;
    __syncthreads();
    const int e0 = hb * CHK;
    for (int i = t; i < CHK; i += 256) {
        int e = e0 + i;
        if (e >= E_) break;
        int src = ei[e], dst = ei[E_ + e];
        int b = dst >> BSH;
        int pos = sbase[b] + atomicAdd(&cnt[b], 1);
        part[pos] = src | ((dst & 255) << 16);
    }
}

// one block per bucket: per-node degree count, LDS scan -> off[], place, flush
__global__ __launch_bounds__(256) void bucket_fill(
    const int* __restrict__ boff, const int* __restrict__ part,
    int* __restrict__ csr, int* __restrict__ off, int n)
{
    __shared__ int sm[256];
    __shared__ int cur[256];
    __shared__ int slice[12544];
    const int t = threadIdx.x;
    const int b = blockIdx.x;
    const int n0 = b << BSH;
    const int nodes = min(256, n - n0);
    const int off0 = boff[b];
    const int sz = boff[b + 1] - off0;

    cur[t] = 0;
    __syncthreads();
    for (int i = t; i < sz; i += 256)
        atomicAdd(&cur[(part[off0 + i] >> 16) & 255], 1);
    __syncthreads();
    int v = cur[t];
    sm[t] = v;
    __syncthreads();
    for (int d = 1; d < 256; d <<= 1) {
        int x = (t >= d) ? sm[t - d] : 0;
        __syncthreads();
        sm[t] += x;
        __syncthreads();
    }
    const int excl = sm[t] - v;
    if (t < nodes) off[n0 + t] = off0 + excl;
    if (t == nodes - 1) off[n0 + nodes] = off0 + sz;
    cur[t] = excl;
    __syncthreads();

    if (sz <= 12544) {
        for (int i = t; i < sz; i += 256) {
            int p  = part[off0 + i];
            int dl = (p >> 16) & 255;
            int pos = atomicAdd(&cur[dl], 1);
            slice[pos] = p & 0xFFFF;
        }
        __syncthreads();
        for (int i = t; i < sz; i += 256)
            csr[off0 + i] = slice[i];
    } else {                                     // fallback (shouldn't trigger)
        for (int i = t; i < sz; i += 256) {
            int p  = part[off0 + i];
            int dl = (p >> 16) & 255;
            int pos = atomicAdd(&cur[dl], 1);
            csr[off0 + pos] = p & 0xFFFF;
        }
    }
}

// ---------------- layer-1 MFMA GEMM (fp32 A, in-register cvt; LDS W) -------
__global__ __launch_bounds__(256) void gemm1_mfma(
    const float* __restrict__ A, const __half* __restrict__ Wt, // [128][128]
    __half* __restrict__ Hout, const float* __restrict__ a_s,
    const float* __restrict__ a_d, float* __restrict__ alS,
    float* __restrict__ alD, int nrows)
{
    constexpr int N = 128, NT = 8, WR = 136;
    __shared__ _Float16 wt[N * WR];
    __shared__ _Float16 hst[4][16 * WR];

    const int t = threadIdx.x, w = t >> 6, l = t & 63;
    const int q = l >> 4, n = l & 15;
    const int node0 = blockIdx.x * 64;
    const int row_base = node0 + w * 16;

    for (int i = t; i < N * 16; i += 256) {
        int r = i >> 4, c = i & 15;
        float4 v = *(const float4*)&Wt[r * 128 + c * 8];
        *(float4*)&wt[r * WR + c * 8] = v;
    }
    __syncthreads();

    f32x4 acc[NT];
#pragma unroll
    for (int ct = 0; ct < NT; ct++) acc[ct] = (f32x4){0.f, 0.f, 0.f, 0.f};

    int arow = row_base + n; if (arow >= nrows) arow = nrows - 1;
    const float* Ap = A + (size_t)arow * 128 + q * 8;
#pragma unroll
    for (int ks = 0; ks < 4; ks++) {
        float4 va = *(const float4*)(Ap + ks * 32);
        float4 vb = *(const float4*)(Ap + ks * 32 + 4);
        f16x8 a = { (_Float16)va.x, (_Float16)va.y, (_Float16)va.z, (_Float16)va.w,
                    (_Float16)vb.x, (_Float16)vb.y, (_Float16)vb.z, (_Float16)vb.w };
#pragma unroll
        for (int ct = 0; ct < NT; ct++) {
            f16x8 bb = *(const f16x8*)&wt[(ct * 16 + n) * WR + ks * 32 + q * 8];
            acc[ct] = __builtin_amdgcn_mfma_f32_16x16x32_f16(a, bb, acc[ct], 0, 0, 0);
        }
    }

    float asv[NT], adv[NT];
#pragma unroll
    for (int ct = 0; ct < NT; ct++) {
        asv[ct] = a_s[ct * 16 + n];
        adv[ct] = a_d[ct * 16 + n];
    }
#pragma unroll
    for (int r = 0; r < 4; r++) {
        int grow = row_base + q * 4 + r;
        float s0 = 0.f, d0 = 0.f, s1 = 0.f, d1 = 0.f;
#pragma unroll
        for (int ct = 0; ct < NT; ct++) {
            float v = acc[ct][r];
            float ps = v * asv[ct], pd = v * adv[ct];
            if (ct >= 4) { s1 += ps; d1 += pd; }
            else         { s0 += ps; d0 += pd; }
        }
#pragma unroll
        for (int m = 1; m < 16; m <<= 1) {
            s0 += __shfl_xor(s0, m); d0 += __shfl_xor(d0, m);
            s1 += __shfl_xor(s1, m); d1 += __shfl_xor(d1, m);
        }
        if (n == 0 && grow < nrows) {
            alS[grow * 2] = s0;     alD[grow * 2] = d0;
            alS[grow * 2 + 1] = s1; alD[grow * 2 + 1] = d1;
        }
    }

#pragma unroll
    for (int ct = 0; ct < NT; ct++)
#pragma unroll
        for (int r = 0; r < 4; r++)
            hst[w][(q * 4 + r) * WR + ct * 16 + n] = (_Float16)acc[ct][r];
    __syncthreads();
    {
        int row = l >> 2, c = l & 3;
        int grow = row_base + row;
        if (grow < nrows) {
#pragma unroll
            for (int i = 0; i < 4; i++) {
                float4 v = *(float4*)&hst[w][row * WR + c * 32 + i * 8];
                *(float4*)&Hout[(size_t)grow * N + c * 32 + i * 8] = v;
            }
        }
    }
}

// ---------------- fused gather (H=2) + next-layer GEMM (LDS-staged W) ------
template<int OUTN>
__global__ __launch_bounds__(256) void gat_gather_gemm(
    const int* __restrict__ off, const int* __restrict__ csr,
    const __half* __restrict__ h, const float* __restrict__ alS,
    const float* __restrict__ alD, const float* __restrict__ bias,
    const __half* __restrict__ Wt, const float* __restrict__ a_s,
    const float* __restrict__ a_d, __half* __restrict__ Hout,
    float* __restrict__ alSo, float* __restrict__ alDo, int n)
{
    constexpr int H = 2, HF = 128, WR = 136;
    constexpr int CTW = OUTN / 64;        // col-tiles per wave
    constexpr int CPW = OUTN / 4;         // cols per wave
    __shared__ _Float16 wls[OUTN * WR];
    __shared__ _Float16 actT[16 * WR];    // act rows; reused for out staging
    __shared__ float red_s[4][16], red_d[4][16];

    const int t = threadIdx.x;
    const int node0 = blockIdx.x * 16;

    // stage Wt early (overlaps gather latency; synced before MFMA use)
    for (int i = t; i < OUTN * 16; i += 256) {
        int r = i >> 4, c = i & 15;
        float4 v = *(const float4*)&Wt[r * 128 + c * 8];
        *(float4*)&wls[r * WR + c * 8] = v;
    }

    // ---- gather ----
    const int l = t & 15;
    const int node = node0 + (t >> 4);
    const bool valid = node < n;
    const int c0 = l * 8;
    const int head = c0 >> 6;
    const int nodec = valid ? node : (n - 1);
    const float ad = alD[nodec * H + head];
    int s0 = 0, s1 = 1;
    if (valid) { s0 = off[node]; s1 = off[node + 1]; }
    const int last = s1 - 1;
    float a0 = 0.f, a1 = 0.f, a2 = 0.f, a3 = 0.f;
    float a4 = 0.f, a5 = 0.f, a6 = 0.f, a7 = 0.f, wsum = 0.f;

    float  as[4];
    float4 v[4];
    {
        int srcs[4];
#pragma unroll
        for (int k = 0; k < 4; k++) {
            int j = s0 + k;
            srcs[k] = csr[j <= last ? j : last];
        }
#pragma unroll
        for (int k = 0; k < 4; k++) {
            as[k] = alS[srcs[k] * H + head];
            v[k]  = *(const float4*)&h[(size_t)srcs[k] * HF + c0];
        }
    }
    for (int j = s0; j < s1; j += 4) {
        int nsrc[4];
#pragma unroll
        for (int k = 0; k < 4; k++) {
            int jj = j + 4 + k;
            nsrc[k] = csr[jj <= last ? jj : last];
        }
        float  nas[4];
        float4 nv[4];
#pragma unroll
        for (int k = 0; k < 4; k++) {
            nas[k] = alS[nsrc[k] * H + head];
            nv[k]  = *(const float4*)&h[(size_t)nsrc[k] * HF + c0];
        }
#pragma unroll
        for (int k = 0; k < 4; k++) {
            float s = as[k] + ad;
            s = s > 0.f ? s : 0.2f * s;     // leaky_relu(0.2)
            float w = __expf(s);
            w = (j + k <= last) ? w : 0.f;
            const __half2* hp = (const __half2*)&v[k];
            float2 f0 = __half22float2(hp[0]);
            float2 f1 = __half22float2(hp[1]);
            float2 f2 = __half22float2(hp[2]);
            float2 f3 = __half22float2(hp[3]);
            a0 = fmaf(w, f0.x, a0); a1 = fmaf(w, f0.y, a1);
            a2 = fmaf(w, f1.x, a2); a3 = fmaf(w, f1.y, a3);
            a4 = fmaf(w, f2.x, a4); a5 = fmaf(w, f2.y, a5);
            a6 = fmaf(w, f3.x, a6); a7 = fmaf(w, f3.y, a7);
            wsum += w;
        }
#pragma unroll
        for (int k = 0; k < 4; k++) { as[k] = nas[k]; v[k] = nv[k]; }
    }
    {
        const float inv = 1.f / (wsum + 1e-16f);
        float4 b0 = *(const float4*)&bias[c0];
        float4 b1 = *(const float4*)&bias[c0 + 4];
        float o[8];
        o[0] = ELU(fmaf(a0, inv, b0.x));
        o[1] = ELU(fmaf(a1, inv, b0.y));
        o[2] = ELU(fmaf(a2, inv, b0.z));
        o[3] = ELU(fmaf(a3, inv, b0.w));
        o[4] = ELU(fmaf(a4, inv, b1.x));
        o[5] = ELU(fmaf(a5, inv, b1.y));
        o[6] = ELU(fmaf(a6, inv, b1.z));
        o[7] = ELU(fmaf(a7, inv, b1.w));
        __half2 p[4];
#pragma unroll
        for (int k = 0; k < 4; k++) p[k] = __floats2half2_rn(o[2 * k], o[2 * k + 1]);
        *(float4*)&actT[(t >> 4) * WR + l * 8] = *(float4*)p;
    }
    __syncthreads();

    // ---- GEMM: D[node][col] = act @ Wt^T ----
    const int w = t >> 6, l64 = t & 63, q = l64 >> 4, nn = l64 & 15;
    f32x4 acc[CTW];
#pragma unroll
    for (int ct = 0; ct < CTW; ct++) acc[ct] = (f32x4){0.f, 0.f, 0.f, 0.f};
#pragma unroll
    for (int ks = 0; ks < 4; ks++) {
        f16x8 a = *(const f16x8*)&actT[nn * WR + ks * 32 + q * 8];
#pragma unroll
        for (int ct = 0; ct < CTW; ct++) {
            f16x8 bb = *(const f16x8*)&wls[(w * CPW + ct * 16 + nn) * WR + ks * 32 + q * 8];
            acc[ct] = __builtin_amdgcn_mfma_f32_16x16x32_f16(a, bb, acc[ct], 0, 0, 0);
        }
    }

    // alS/alD partials: reduce over this wave's cols, then across waves (LDS)
    float asv[CTW], adv[CTW];
#pragma unroll
    for (int ct = 0; ct < CTW; ct++) {
        asv[ct] = a_s[w * CPW + ct * 16 + nn];
        adv[ct] = a_d[w * CPW + ct * 16 + nn];
    }
#pragma unroll
    for (int r = 0; r < 4; r++) {
        float s = 0.f, d = 0.f;
#pragma unroll
        for (int ct = 0; ct < CTW; ct++) {
            float vv = acc[ct][r];
            s = fmaf(vv, asv[ct], s);
            d = fmaf(vv, adv[ct], d);
        }
#pragma unroll
        for (int m = 1; m < 16; m <<= 1) {
            s += __shfl_xor(s, m);
            d += __shfl_xor(d, m);
        }
        if (nn == 0) { red_s[w][q * 4 + r] = s; red_d[w][q * 4 + r] = d; }
    }
    __syncthreads();

    // stage output into actT (reuse) + combine alS across waves
#pragma unroll
    for (int ct = 0; ct < CTW; ct++)
#pragma unroll
        for (int r = 0; r < 4; r++)
            actT[(q * 4 + r) * WR + w * CPW + ct * 16 + nn] = (_Float16)acc[ct][r];
    if (OUTN == 128) {
        if (t < 32) {
            int m = t & 15, hh = t >> 4;
            int grow = node0 + m;
            if (grow < n) {
                alSo[grow * 2 + hh] = red_s[2 * hh][m] + red_s[2 * hh + 1][m];
                alDo[grow * 2 + hh] = red_d[2 * hh][m] + red_d[2 * hh + 1][m];
            }
        }
    } else {
        if (t < 16) {
            int grow = node0 + t;
            if (grow < n) {
                alSo[grow] = red_s[0][t] + red_s[1][t] + red_s[2][t] + red_s[3][t];
                alDo[grow] = red_d[0][t] + red_d[1][t] + red_d[2][t] + red_d[3][t];
            }
        }
    }
    __syncthreads();

    // coalesced Hout store
    if (OUTN == 128) {
        int row = t >> 4, c = t & 15;
        int grow = node0 + row;
        if (grow < n)
            *(float4*)&Hout[(size_t)grow * 128 + c * 8] = *(float4*)&actT[row * WR + c * 8];
    } else {
        if (t < 128) {
            int row = t >> 3, c = t & 7;
            int grow = node0 + row;
            if (grow < n)
                *(float4*)&Hout[(size_t)grow * 64 + c * 8] = *(float4*)&actT[row * WR + c * 8];
        }
    }
}

// ---------------- final gather (H=1) -> fp32 out ---------------------------
__global__ __launch_bounds__(256) void gat_gather_out(
    const int* __restrict__ off, const int* __restrict__ csr,
    const __half* __restrict__ h, const float* __restrict__ alS,
    const float* __restrict__ alD, const float* __restrict__ b,
    float* __restrict__ out, int n)
{
    constexpr int HF = 64, LPN = 8, NPB = 32;
    const int l    = threadIdx.x % LPN;
    const int node = blockIdx.x * NPB + threadIdx.x / LPN;
    if (node >= n) return;
    const int c0   = l * 8;
    const float ad = alD[node];

    const int s0 = off[node], s1 = off[node + 1];
    const int last = s1 - 1;
    float a0 = 0.f, a1 = 0.f, a2 = 0.f, a3 = 0.f;
    float a4 = 0.f, a5 = 0.f, a6 = 0.f, a7 = 0.f, wsum = 0.f;

    float  as[4];
    float4 v[4];
    {
        int srcs[4];
#pragma unroll
        for (int k = 0; k < 4; k++) {
            int j = s0 + k;
            srcs[k] = csr[j <= last ? j : last];
        }
#pragma unroll
        for (int k = 0; k < 4; k++) {
            as[k] = alS[srcs[k]];
            v[k]  = *(const float4*)&h[(size_t)srcs[k] * HF + c0];
        }
    }
    for (int j = s0; j < s1; j += 4) {
        int nsrc[4];
#pragma unroll
        for (int k = 0; k < 4; k++) {
            int jj = j + 4 + k;
            nsrc[k] = csr[jj <= last ? jj : last];
        }
        float  nas[4];
        float4 nv[4];
#pragma unroll
        for (int k = 0; k < 4; k++) {
            nas[k] = alS[nsrc[k]];
            nv[k]  = *(const float4*)&h[(size_t)nsrc[k] * HF + c0];
        }
#pragma unroll
        for (int k = 0; k < 4; k++) {
            float s = as[k] + ad;
            s = s > 0.f ? s : 0.2f * s;
            float w = __expf(s);
            w = (j + k <= last) ? w : 0.f;
            const __half2* hp = (const __half2*)&v[k];
            float2 f0 = __half22float2(hp[0]);
            float2 f1 = __half22float2(hp[1]);
            float2 f2 = __half22float2(hp[2]);
            float2 f3 = __half22float2(hp[3]);
            a0 = fmaf(w, f0.x, a0); a1 = fmaf(w, f0.y, a1);
            a2 = fmaf(w, f1.x, a2); a3 = fmaf(w, f1.y, a3);
            a4 = fmaf(w, f2.x, a4); a5 = fmaf(w, f2.y, a5);
            a6 = fmaf(w, f3.x, a6); a7 = fmaf(w, f3.y, a7);
            wsum += w;
        }
#pragma unroll
        for (int k = 0; k < 4; k++) { as[k] = nas[k]; v[k] = nv[k]; }
    }

    const float inv = 1.f / (wsum + 1e-16f);
    float4 b0 = *(const float4*)&b[c0];
    float4 b1 = *(const float4*)&b[c0 + 4];
    float4 o0, o1;
    o0.x = ELU(fmaf(a0, inv, b0.x));
    o0.y = ELU(fmaf(a1, inv, b0.y));
    o0.z = ELU(fmaf(a2, inv, b0.z));
    o0.w = ELU(fmaf(a3, inv, b0.w));
    o1.x = ELU(fmaf(a4, inv, b1.x));
    o1.y = ELU(fmaf(a5, inv, b1.y));
    o1.z = ELU(fmaf(a6, inv, b1.z));
    o1.w = ELU(fmaf(a7, inv, b1.w));
    *(float4*)&out[(size_t)node * HF + c0]     = o0;
    *(float4*)&out[(size_t)node * HF + c0 + 4] = o1;
}

extern "C" void kernel_launch(void* const* d_in, const int* in_sizes, int n_in,
                              void* d_out, int out_size, void* d_ws, size_t ws_size,
                              hipStream_t stream)
{
    const float* x   = (const float*)d_in[0];
    const float* W1  = (const float*)d_in[1];
    const float* as1 = (const float*)d_in[2];
    const float* ad1 = (const float*)d_in[3];
    const float* b1  = (const float*)d_in[4];
    const float* W2  = (const float*)d_in[5];
    const float* as2 = (const float*)d_in[6];
    const float* ad2 = (const float*)d_in[7];
    const float* b2  = (const float*)d_in[8];
    const float* W3  = (const float*)d_in[9];
    const float* as3 = (const float*)d_in[10];
    const float* ad3 = (const float*)d_in[11];
    const float* b3  = (const float*)d_in[12];
    const int*   ei  = (const int*)d_in[13];
    float* out = (float*)d_out;

    const int N_   = in_sizes[0] / 128;     // 50000
    const int E_   = in_sizes[13] / 2;      // 1600000
    const int Etot = E_ + N_;
    const int NB   = (N_ + 255) >> BSH;     // 196 buckets
    const int HB   = (E_ + CHK - 1) / CHK;  // 196 hist/partition blocks

    char* ws = (char*)d_ws;
    size_t o = 0;
    auto alloc = [&](size_t bytes) { void* p = ws + o; o += (bytes + 255) & ~255ull; return p; };
    __half* h1    = (__half*)alloc((size_t)N_ * 128 * 2);
    __half* h2    = (__half*)alloc((size_t)N_ * 128 * 2);
    __half* h3    = (__half*)alloc((size_t)N_ * 64 * 2);
    __half* Wt1   = (__half*)alloc((size_t)128 * 128 * 2);
    __half* Wt2   = (__half*)alloc((size_t)128 * 128 * 2);
    __half* Wt3   = (__half*)alloc((size_t)64 * 128 * 2);
    float* alSa   = (float*)alloc((size_t)N_ * 2 * 4);
    float* alDa   = (float*)alloc((size_t)N_ * 2 * 4);
    float* alSb   = (float*)alloc((size_t)N_ * 2 * 4);
    float* alDb   = (float*)alloc((size_t)N_ * 2 * 4);
    int*   offb   = (int*)alloc((size_t)(N_ + 1) * 4);
    int*   bhrows = (int*)alloc((size_t)HB * 256 * 4);
    int*   boff   = (int*)alloc((size_t)257 * 4);
    int*   bases  = (int*)alloc((size_t)256 * HB * 4);
    int*   part   = (int*)alloc((size_t)Etot * 4);
    int*   csr    = (int*)alloc((size_t)Etot * 4);

    const dim3 blk(256);

    // ---- phase0 + CSR build (no global atomics anywhere) ----
    phase0<<<160 + HB, blk, 0, stream>>>(W1, Wt1, W2, Wt2, W3, Wt3, ei, bhrows, E_);
    scan_bases<<<NB, blk, 0, stream>>>(bhrows, boff, bases, part, HB, N_, NB);
    edge_partition<<<HB, blk, 0, stream>>>(ei, bases, part, E_, HB, NB);
    bucket_fill<<<NB, blk, 0, stream>>>(boff, part, csr, offb, N_);

    // ---- layer pipeline ----
    gemm1_mfma<<<(N_ + 63) / 64, blk, 0, stream>>>(x, Wt1, h1, as1, ad1, alSa, alDa, N_);
    gat_gather_gemm<128><<<(N_ + 15) / 16, blk, 0, stream>>>(
        offb, csr, h1, alSa, alDa, b1, Wt2, as2, ad2, h2, alSb, alDb, N_);
    gat_gather_gemm<64><<<(N_ + 15) / 16, blk, 0, stream>>>(
        offb, csr, h2, alSb, alDb, b2, Wt3, as3, ad3, h3, alSa, alDa, N_);
    gat_gather_out<<<(N_ + 31) / 32, blk, 0, stream>>>(
        offb, csr, h3, alSa, alDa, b3, out, N_);
}